// Round 11
// baseline (125.040 us; speedup 1.0000x reference)
//
#include <hip/hip_runtime.h>
#include <hip/hip_bf16.h>

// Linear attention (ELU feature map) via bf16 MFMA with hi/lo split-precision.
//   K1 (R11): full-row blocks + float4 staging + 64KB LDS tile.
//       1024 threads = 16 waves; wave = (head, d-half). Per 32-row tile:
//       stage K (float4, 1KB/instr contiguous) -> A-frags; stage V -> B-frags
//       + MFMA. V/next-K loads issued one phase early. NSPL=8 (256 blocks).
//   K1R: reduce 8 partials in-place into partial slot 0 (1024 blocks).
//   K2: O = phiQ*KV, Z via MFMA (R6-verified), reads the reduced partial.
// Fallback (ws too small): fp32 fused kernel (R1, verified).

constexpr int Bc = 4, Nc = 8, Hc = 8;
constexpr int Lc = 1024, Sc = 1024, Dc = 64, Mc = 64;
constexpr int HD = Hc * Dc;            // 512 floats between consecutive rows
constexpr int GROUPS = Bc * Nc * Hc;   // 256
constexpr int BN = Bc * Nc;            // 32
constexpr int LSPLITS = 4;
constexpr int LROWS = Lc / LSPLITS;    // 256
constexpr int PARTIAL = Dc * Mc + Dc;  // 4160 floats per partial
constexpr int NTL = LROWS / 64;        // 4 l-tiles
constexpr int PADD = 68;               // K2 inner dim: 64 d + 4 pad (bf16)
constexpr float EPSF = 1e-6f;

typedef __attribute__((ext_vector_type(8))) __bf16 bf16x8;
typedef __attribute__((ext_vector_type(4))) float f32x4;

__device__ __forceinline__ float elup1(float x) {
    return x > 0.0f ? x + 1.0f : __expf(x);
}
__device__ __forceinline__ unsigned short f2bf(float f) {
    unsigned u = __builtin_bit_cast(unsigned, f);
    u += 0x7fffu + ((u >> 16) & 1u);          // round-to-nearest-even
    return (unsigned short)(u >> 16);
}
__device__ __forceinline__ float bf2f(unsigned short h) {
    return __builtin_bit_cast(float, (unsigned)h << 16);
}
__device__ __forceinline__ void splitbf(float x, unsigned short& h, unsigned short& l) {
    h = f2bf(x);
    l = f2bf(x - bf2f(h));
}
__device__ __forceinline__ unsigned pack2(unsigned short lo, unsigned short hi) {
    return (unsigned)lo | ((unsigned)hi << 16);
}
__device__ __forceinline__ bf16x8 ones_frag() {
    union { bf16x8 v; unsigned short s[8]; } u;
    #pragma unroll
    for (int i = 0; i < 8; ++i) u.s[i] = 0x3F80;   // bf16 1.0
    return u.v;
}

// ------- Kernel 1: partial KV, full-row float4 staging through 64KB LDS -----
template<int NSPL>
__global__ void __launch_bounds__(1024, 1)
la_kv_fullrow2(const float* __restrict__ Kg, const float* __restrict__ Vg,
               const float* __restrict__ Mg, float* __restrict__ ws)
{
    constexpr int SR = Sc / NSPL;      // 128 s-rows per block
    constexpr int NT = SR / 32;        // 4 tiles of 32 rows

    __shared__ float tl[32][512];      // 64 KB, shared by K-phase then V-phase

    const int t     = threadIdx.x;
    const int lane  = t & 63;
    const int w     = t >> 6;          // wave 0..15
    const int h     = w >> 1;          // head 0..7
    const int dhalf = w & 1;           // d-half 0..1
    const int frow  = lane & 15;
    const int kg    = lane >> 4;       // k-group 0..3
    const int bn    = blockIdx.y;
    const int sp    = blockIdx.x;
    const int b     = bn >> 3;

    const size_t slab  = (size_t)bn * Sc * HD;
    const size_t mbase = (size_t)b * Sc;
    const int    sbase = sp * SR;

    // staging: thread t covers rows (t>>7)+8q, float-cols 4*(t&127)..+3
    const int srow = t >> 7;           // 0..7
    const int scol = (t & 127) * 4;    // 0..508

    f32x4 acc[2][4];                   // [d-chunk within half][m-chunk]
    f32x4 aks[2];
    #pragma unroll
    for (int c = 0; c < 2; ++c) {
        aks[c] = (f32x4){0.f, 0.f, 0.f, 0.f};
        #pragma unroll
        for (int ms = 0; ms < 4; ++ms) acc[c][ms] = (f32x4){0.f, 0.f, 0.f, 0.f};
    }
    const bf16x8 ones = ones_frag();
    union uf { bf16x8 v; unsigned short s[8]; };

    float4 stK[4], stV[4];
    auto ldK = [&](int it) {
        #pragma unroll
        for (int q = 0; q < 4; ++q)
            stK[q] = *reinterpret_cast<const float4*>(
                Kg + slab + (size_t)(sbase + it * 32 + srow + 8 * q) * HD + scol);
    };
    auto ldV = [&](int it) {
        #pragma unroll
        for (int q = 0; q < 4; ++q)
            stV[q] = *reinterpret_cast<const float4*>(
                Vg + slab + (size_t)(sbase + it * 32 + srow + 8 * q) * HD + scol);
    };

    ldK(0);
    for (int it = 0; it < NT; ++it) {
        // ---- K phase: store staged K tile ----
        #pragma unroll
        for (int q = 0; q < 4; ++q)
            *reinterpret_cast<float4*>(&tl[srow + 8 * q][scol]) = stK[q];
        __syncthreads();
        ldV(it);                         // V loads fly during A-frag phase

        // A-frags: K[s=8kg+j][d = 64h + 32dhalf + 16c + frow]
        const int s0 = sbase + it * 32;
        float ml[8];
        #pragma unroll
        for (int j = 0; j < 8; ++j) ml[j] = Mg[mbase + s0 + 8 * kg + j];
        uf kh[2], kl[2];
        #pragma unroll
        for (int c = 0; c < 2; ++c) {
            #pragma unroll
            for (int j = 0; j < 8; ++j) {
                const float ka = tl[8 * kg + j][64 * h + 32 * dhalf + 16 * c + frow];
                splitbf(elup1(ka) * ml[j], kh[c].s[j], kl[c].s[j]);
            }
            aks[c] = __builtin_amdgcn_mfma_f32_16x16x32_bf16(kh[c].v, ones, aks[c], 0, 0, 0);
            aks[c] = __builtin_amdgcn_mfma_f32_16x16x32_bf16(kl[c].v, ones, aks[c], 0, 0, 0);
        }
        __syncthreads();

        // ---- V phase: store staged V tile ----
        #pragma unroll
        for (int q = 0; q < 4; ++q)
            *reinterpret_cast<float4*>(&tl[srow + 8 * q][scol]) = stV[q];
        __syncthreads();
        if (it + 1 < NT) ldK(it + 1);    // next-K loads fly during MFMA phase

        // B-frags + MFMA: V[s=8kg+j][m = 64h + 16ms + frow]
        #pragma unroll
        for (int ms = 0; ms < 4; ++ms) {
            uf vh, vl;
            #pragma unroll
            for (int j = 0; j < 8; ++j) {
                const float vb = tl[8 * kg + j][64 * h + 16 * ms + frow];
                splitbf(vb, vh.s[j], vl.s[j]);
            }
            #pragma unroll
            for (int c = 0; c < 2; ++c) {
                acc[c][ms] = __builtin_amdgcn_mfma_f32_16x16x32_bf16(kh[c].v, vh.v, acc[c][ms], 0, 0, 0);
                acc[c][ms] = __builtin_amdgcn_mfma_f32_16x16x32_bf16(kh[c].v, vl.v, acc[c][ms], 0, 0, 0);
                acc[c][ms] = __builtin_amdgcn_mfma_f32_16x16x32_bf16(kl[c].v, vh.v, acc[c][ms], 0, 0, 0);
            }
        }
        __syncthreads();                 // tl free for next tile
    }

    // write this wave's (head h, d-half) partial slice
    float* outp = ws + (size_t)((bn * 8 + h) * NSPL + sp) * PARTIAL;
    #pragma unroll
    for (int c = 0; c < 2; ++c)
        #pragma unroll
        for (int ms = 0; ms < 4; ++ms)
            #pragma unroll
            for (int r = 0; r < 4; ++r)
                outp[(32 * dhalf + 16 * c + 4 * kg + r) * Mc + 16 * ms + frow] = acc[c][ms][r];

    if (frow == 0) {
        #pragma unroll
        for (int c = 0; c < 2; ++c)
            #pragma unroll
            for (int r = 0; r < 4; ++r)
                outp[Dc * Mc + 32 * dhalf + 16 * c + 4 * kg + r] = aks[c][r];
    }
}

// ------- Kernel 1R: reduce NSPL partials in place into partial slot 0 -------
template<int NSPL>
__global__ void __launch_bounds__(256, 8)
la_reduce(float* __restrict__ ws)
{
    constexpr int NF4 = PARTIAL / 4;     // 1040 float4s
    constexpr int QW  = NF4 / 4;         // 260 per quarter-block
    const int g = blockIdx.y;            // group 0..255
    const int q = blockIdx.x;            // quarter 0..3
    const int t = threadIdx.x;

    float4* base = reinterpret_cast<float4*>(ws + (size_t)g * NSPL * PARTIAL);
    for (int i = q * QW + t; i < (q + 1) * QW; i += 256) {
        float4 s = base[i];
        #pragma unroll
        for (int sp = 1; sp < NSPL; ++sp) {
            const float4 p = base[sp * NF4 + i];
            s.x += p.x; s.y += p.y; s.z += p.z; s.w += p.w;
        }
        base[i] = s;                     // in-place: slot 0 now holds the sum
    }
}

// ---------------- Kernel 2: output via split-bf16 MFMA (R6, verified) --------
// NSUM = partials to sum (1 after la_reduce); pstride = slots per group in ws.
template<int NSUM>
__global__ void __launch_bounds__(256, 4)
la_out_mfma(const float* __restrict__ Qg, const float* __restrict__ ws,
            float* __restrict__ Og, int pstride)
{
    __shared__ unsigned short kvh[Mc][PADD];  // KV hi [m][d]
    __shared__ unsigned short kvl[Mc][PADD];  // KV lo
    __shared__ unsigned short ksh[64];        // ksum hi
    __shared__ unsigned short ksl[64];        // ksum lo
    __shared__ unsigned short qhh[64][PADD];  // phiQ hi [l][d]
    __shared__ unsigned short qll[64][PADD];  // phiQ lo

    const int t    = threadIdx.x;
    const int tx   = t & 15;
    const int tyq  = t >> 4;
    const int lane = t & 63;
    const int w    = t >> 6;
    const int g    = blockIdx.y;
    const int ls   = blockIdx.x;
    const int h    = g & 7;
    const int bn   = g >> 3;

    const size_t rowbase = (size_t)bn * Lc * HD + (size_t)h * Dc;
    const float* pw = ws + (size_t)g * pstride * PARTIAL;
    const int lbase = ls * LROWS;

    float4 qr[4];
    auto loadB = [&](int it) {
        const int l0 = lbase + it * 64 + 4 * tyq;
        #pragma unroll
        for (int j = 0; j < 4; ++j)
            qr[j] = *reinterpret_cast<const float4*>(Qg + rowbase + (size_t)(l0 + j) * HD + 4 * tx);
    };
    auto storeB = [&]() {
        #pragma unroll
        for (int j = 0; j < 4; ++j) {
            const int r = 4 * tyq + j;
            const float q[4] = {qr[j].x, qr[j].y, qr[j].z, qr[j].w};
            unsigned short h0, l0, h1, l1, h2, l2, h3, l3;
            splitbf(elup1(q[0]), h0, l0);
            splitbf(elup1(q[1]), h1, l1);
            splitbf(elup1(q[2]), h2, l2);
            splitbf(elup1(q[3]), h3, l3);
            uint2 ph, pl;
            ph.x = pack2(h0, h1); ph.y = pack2(h2, h3);
            pl.x = pack2(l0, l1); pl.y = pack2(l2, l3);
            *reinterpret_cast<uint2*>(&qhh[r][4 * tx]) = ph;
            *reinterpret_cast<uint2*>(&qll[r][4 * tx]) = pl;
        }
    };

    loadB(0);
    #pragma unroll
    for (int e = 0; e < 16; ++e) {
        const int idx = t + 256 * e;
        float s = 0.f;
        #pragma unroll
        for (int sp = 0; sp < NSUM; ++sp) s += pw[sp * PARTIAL + idx];
        unsigned short hh, ll;
        splitbf(s, hh, ll);
        kvh[idx & 63][idx >> 6] = hh;
        kvl[idx & 63][idx >> 6] = ll;
    }
    if (t < 64) {
        float s = 0.f;
        #pragma unroll
        for (int sp = 0; sp < NSUM; ++sp) s += pw[sp * PARTIAL + Dc * Mc + t];
        unsigned short hh, ll;
        splitbf(s, hh, ll);
        ksh[t] = hh;
        ksl[t] = ll;
    }
    storeB();
    __syncthreads();

    const int fcol = 8 * (lane >> 4);
    const int frow = lane & 15;
    const size_t obase = (size_t)bn * Lc * HD + (size_t)h * Mc;

    for (int it = 0; it < NTL; ++it) {
        if (it + 1 < NTL) loadB(it + 1);
        union { bf16x8 v; uint2 u[2]; } fah0, fal0, fah1, fal1;
        {
            const uint2* p;
            p = reinterpret_cast<const uint2*>(&qhh[16 * w + frow][fcol]);      fah0.u[0] = p[0]; fah0.u[1] = p[1];
            p = reinterpret_cast<const uint2*>(&qll[16 * w + frow][fcol]);      fal0.u[0] = p[0]; fal0.u[1] = p[1];
            p = reinterpret_cast<const uint2*>(&qhh[16 * w + frow][32 + fcol]); fah1.u[0] = p[0]; fah1.u[1] = p[1];
            p = reinterpret_cast<const uint2*>(&qll[16 * w + frow][32 + fcol]); fal1.u[0] = p[0]; fal1.u[1] = p[1];
        }
        f32x4 acc[4], accz;
        #pragma unroll
        for (int ms = 0; ms < 4; ++ms) acc[ms] = (f32x4){0.f, 0.f, 0.f, 0.f};
        accz = (f32x4){0.f, 0.f, 0.f, 0.f};

        #pragma unroll
        for (int ks = 0; ks < 2; ++ks) {
            const bf16x8 fh = ks ? fah1.v : fah0.v;
            const bf16x8 fl = ks ? fal1.v : fal0.v;
            #pragma unroll
            for (int ms = 0; ms < 4; ++ms) {
                union { bf16x8 v; uint2 u[2]; } fbh, fbl;
                const uint2* ph = reinterpret_cast<const uint2*>(&kvh[16 * ms + frow][32 * ks + fcol]);
                fbh.u[0] = ph[0]; fbh.u[1] = ph[1];
                const uint2* pl = reinterpret_cast<const uint2*>(&kvl[16 * ms + frow][32 * ks + fcol]);
                fbl.u[0] = pl[0]; fbl.u[1] = pl[1];
                acc[ms] = __builtin_amdgcn_mfma_f32_16x16x32_bf16(fh, fbh.v, acc[ms], 0, 0, 0);
                acc[ms] = __builtin_amdgcn_mfma_f32_16x16x32_bf16(fh, fbl.v, acc[ms], 0, 0, 0);
                acc[ms] = __builtin_amdgcn_mfma_f32_16x16x32_bf16(fl, fbh.v, acc[ms], 0, 0, 0);
            }
            union { bf16x8 v; uint2 u[2]; } fzh, fzl;
            const uint2* ph = reinterpret_cast<const uint2*>(&ksh[32 * ks + fcol]);
            fzh.u[0] = ph[0]; fzh.u[1] = ph[1];
            const uint2* pl = reinterpret_cast<const uint2*>(&ksl[32 * ks + fcol]);
            fzl.u[0] = pl[0]; fzl.u[1] = pl[1];
            accz = __builtin_amdgcn_mfma_f32_16x16x32_bf16(fh, fzh.v, accz, 0, 0, 0);
            accz = __builtin_amdgcn_mfma_f32_16x16x32_bf16(fh, fzl.v, accz, 0, 0, 0);
            accz = __builtin_amdgcn_mfma_f32_16x16x32_bf16(fl, fzh.v, accz, 0, 0, 0);
        }

        const int lt = lbase + it * 64 + 16 * w + 4 * (lane >> 4);
        #pragma unroll
        for (int r = 0; r < 4; ++r) {
            const float z = 1.0f / (accz[r] + EPSF);
            const size_t ro = obase + (size_t)(lt + r) * HD + frow;
            #pragma unroll
            for (int ms = 0; ms < 4; ++ms)
                Og[ro + 16 * ms] = acc[ms][r] * z;
        }
        __syncthreads();
        if (it + 1 < NTL) storeB();
        __syncthreads();
    }
}

// ---------------- Fallback: fp32 fused kernel (verified R1) ----------------
__global__ void __launch_bounds__(256, 1)
la_fused_kernel(const float* __restrict__ Qg, const float* __restrict__ Kg,
                const float* __restrict__ Vg, const float* __restrict__ Mg,
                float* __restrict__ Og)
{
    __shared__ float lk[32][Dc];
    __shared__ float lv[32][Mc];
    __shared__ float kvt[Dc][Mc];
    __shared__ float ksm[Dc];
    __shared__ float qt[Dc][64];

    const int t  = threadIdx.x;
    const int tx = t & 15;
    const int ty = t >> 4;
    const int g  = blockIdx.x;
    const int h  = g & 7;
    const int bn = g >> 3;
    const int b  = g >> 6;

    const size_t rowbase = (size_t)bn * Sc * HD + (size_t)h * Dc;
    const size_t mbase   = (size_t)b * Sc;

    const int d0 = tx * 4, m0 = ty * 4, c4 = tx * 4, r0 = ty;

    float acc[4][4] = {{0.f,0.f,0.f,0.f},{0.f,0.f,0.f,0.f},{0.f,0.f,0.f,0.f},{0.f,0.f,0.f,0.f}};
    float ks[4] = {0.f, 0.f, 0.f, 0.f};
    float4 kr[2], vr[2];
    float  mr[2];

    auto loadA = [&](int it) {
        const int s0 = it * 32;
        #pragma unroll
        for (int k = 0; k < 2; ++k) {
            const int r = r0 + 16 * k;
            const size_t off = rowbase + (size_t)(s0 + r) * HD + c4;
            kr[k] = *reinterpret_cast<const float4*>(Kg + off);
            vr[k] = *reinterpret_cast<const float4*>(Vg + off);
            mr[k] = Mg[mbase + s0 + r];
        }
    };
    auto storeA = [&]() {
        #pragma unroll
        for (int k = 0; k < 2; ++k) {
            const int r = r0 + 16 * k;
            float4 kk;
            kk.x = elup1(kr[k].x) * mr[k];
            kk.y = elup1(kr[k].y) * mr[k];
            kk.z = elup1(kr[k].z) * mr[k];
            kk.w = elup1(kr[k].w) * mr[k];
            *reinterpret_cast<float4*>(&lk[r][c4]) = kk;
            *reinterpret_cast<float4*>(&lv[r][c4]) = vr[k];
        }
    };

    loadA(0);
    storeA();
    __syncthreads();
    for (int it = 0; it < Sc / 32; ++it) {
        if (it + 1 < Sc / 32) loadA(it + 1);
        #pragma unroll 8
        for (int r = 0; r < 32; ++r) {
            const float4 k4 = *reinterpret_cast<const float4*>(&lk[r][d0]);
            const float4 v4 = *reinterpret_cast<const float4*>(&lv[r][m0]);
            const float kk[4] = {k4.x, k4.y, k4.z, k4.w};
            const float vv[4] = {v4.x, v4.y, v4.z, v4.w};
            ks[0] += kk[0]; ks[1] += kk[1]; ks[2] += kk[2]; ks[3] += kk[3];
            #pragma unroll
            for (int i = 0; i < 4; ++i)
                #pragma unroll
                for (int j = 0; j < 4; ++j)
                    acc[i][j] += kk[i] * vv[j];
        }
        __syncthreads();
        if (it + 1 < Sc / 32) storeA();
        __syncthreads();
    }

    #pragma unroll
    for (int i = 0; i < 4; ++i) {
        float4 w;
        w.x = acc[i][0]; w.y = acc[i][1]; w.z = acc[i][2]; w.w = acc[i][3];
        *reinterpret_cast<float4*>(&kvt[d0 + i][m0]) = w;
    }
    if (ty == 0) {
        #pragma unroll
        for (int i = 0; i < 4; ++i) ksm[d0 + i] = ks[i];
    }
    __syncthreads();

    float4 qr[4];
    auto loadB = [&](int it) {
        const int l0 = it * 64;
        #pragma unroll
        for (int k = 0; k < 4; ++k) {
            const int r = r0 + 16 * k;
            const size_t off = rowbase + (size_t)(l0 + r) * HD + c4;
            qr[k] = *reinterpret_cast<const float4*>(Qg + off);
        }
    };
    const int swzw = (tx & 7) << 2;
    auto storeB = [&]() {
        #pragma unroll
        for (int k = 0; k < 4; ++k) {
            const int r = r0 + 16 * k;
            const int lidx = r ^ swzw;
            qt[c4 + 0][lidx] = elup1(qr[k].x);
            qt[c4 + 1][lidx] = elup1(qr[k].y);
            qt[c4 + 2][lidx] = elup1(qr[k].z);
            qt[c4 + 3][lidx] = elup1(qr[k].w);
        }
    };

    loadB(0);
    storeB();
    __syncthreads();
    for (int it = 0; it < Lc / 64; ++it) {
        if (it + 1 < Lc / 64) loadB(it + 1);
        float accB[4][4] = {{0.f,0.f,0.f,0.f},{0.f,0.f,0.f,0.f},{0.f,0.f,0.f,0.f},{0.f,0.f,0.f,0.f}};
        float za[4] = {0.f, 0.f, 0.f, 0.f};
        #pragma unroll 8
        for (int d = 0; d < Dc; ++d) {
            const int swz = ((d >> 2) & 7) << 2;
            const float4 q4  = *reinterpret_cast<const float4*>(&qt[d][(4 * ty) ^ swz]);
            const float4 kv4 = *reinterpret_cast<const float4*>(&kvt[d][4 * tx]);
            const float kd = ksm[d];
            const float qq[4] = {q4.x, q4.y, q4.z, q4.w};
            const float kv[4] = {kv4.x, kv4.y, kv4.z, kv4.w};
            #pragma unroll
            for (int i = 0; i < 4; ++i) {
                za[i] += qq[i] * kd;
                #pragma unroll
                for (int j = 0; j < 4; ++j)
                    accB[i][j] += qq[i] * kv[j];
            }
        }
        const int l0 = it * 64;
        const size_t obase = (size_t)bn * Lc * HD + (size_t)h * Mc;
        #pragma unroll
        for (int i = 0; i < 4; ++i) {
            const int l = l0 + 4 * ty + i;
            const float z = 1.0f / (za[i] + EPSF);
            float4 o;
            o.x = accB[i][0] * z; o.y = accB[i][1] * z;
            o.z = accB[i][2] * z; o.w = accB[i][3] * z;
            *reinterpret_cast<float4*>(Og + obase + (size_t)l * HD + 4 * tx) = o;
        }
        __syncthreads();
        if (it + 1 < Lc / 64) storeB();
        __syncthreads();
    }
}

extern "C" void kernel_launch(void* const* d_in, const int* in_sizes, int n_in,
                              void* d_out, int out_size, void* d_ws, size_t ws_size,
                              hipStream_t stream) {
    const float* Qg = (const float*)d_in[0];
    const float* Kg = (const float*)d_in[1];
    const float* Vg = (const float*)d_in[2];
    const float* Mg = (const float*)d_in[3];
    float* Og = (float*)d_out;

    const size_t need8 = (size_t)GROUPS * 8 * PARTIAL * sizeof(float);
    if (ws_size >= need8) {
        float* ws = (float*)d_ws;
        hipLaunchKernelGGL((la_kv_fullrow2<8>), dim3(8, BN), dim3(1024), 0, stream,
                           Kg, Vg, Mg, ws);
        hipLaunchKernelGGL((la_reduce<8>), dim3(4, GROUPS), dim3(256), 0, stream,
                           ws);
        hipLaunchKernelGGL((la_out_mfma<1>), dim3(LSPLITS, GROUPS), dim3(256), 0, stream,
                           Qg, ws, Og, 8);
    } else {
        hipLaunchKernelGGL(la_fused_kernel, dim3(GROUPS), dim3(256), 0, stream,
                           Qg, Kg, Vg, Mg, Og);
    }
}

// Round 12
// 80.867 us; speedup vs baseline: 1.5462x; 1.5462x over previous
//
#include <hip/hip_runtime.h>
#include <hip/hip_bf16.h>

// Linear attention (ELU feature map) via bf16 MFMA with hi/lo split-precision.
//   K1 (R12): no-LDS no-barrier direct-gather (R10-proven) with deep load
//       clauses: wave = (head, d-half) -> acc 40 VGPR, ALL tile loads hoisted
//       before use (~32 outstanding/wave). 512-thr blocks per (s-split,
//       head-quad) read 1KB-contiguous half-rows; 512 blocks = 2/CU. NSPL=8.
//   K1R: reduce 8 partials in-place into slot 0 (verified R11).
//   K2: O = phiQ*KV, Z via MFMA, hi/lo split, NSUM=1 (verified R11).
// Fallback (ws too small): fp32 fused kernel (R1, verified).

constexpr int Bc = 4, Nc = 8, Hc = 8;
constexpr int Lc = 1024, Sc = 1024, Dc = 64, Mc = 64;
constexpr int HD = Hc * Dc;            // 512 floats between consecutive rows
constexpr int GROUPS = Bc * Nc * Hc;   // 256
constexpr int BN = Bc * Nc;            // 32
constexpr int LSPLITS = 4;
constexpr int LROWS = Lc / LSPLITS;    // 256
constexpr int PARTIAL = Dc * Mc + Dc;  // 4160 floats per partial
constexpr int NTL = LROWS / 64;        // 4 l-tiles
constexpr int PADD = 68;               // K2 inner dim: 64 d + 4 pad (bf16)
constexpr float EPSF = 1e-6f;

typedef __attribute__((ext_vector_type(8))) __bf16 bf16x8;
typedef __attribute__((ext_vector_type(4))) float f32x4;

__device__ __forceinline__ float elup1(float x) {
    return x > 0.0f ? x + 1.0f : __expf(x);
}
__device__ __forceinline__ unsigned short f2bf(float f) {
    unsigned u = __builtin_bit_cast(unsigned, f);
    u += 0x7fffu + ((u >> 16) & 1u);          // round-to-nearest-even
    return (unsigned short)(u >> 16);
}
__device__ __forceinline__ float bf2f(unsigned short h) {
    return __builtin_bit_cast(float, (unsigned)h << 16);
}
// split x into hi+lo bf16 (lo = rounding residue, |lo| <= 2^-9 |x|)
__device__ __forceinline__ void splitbf(float x, unsigned short& h, unsigned short& l) {
    h = f2bf(x);
    l = f2bf(x - bf2f(h));
}
__device__ __forceinline__ unsigned pack2(unsigned short lo, unsigned short hi) {
    return (unsigned)lo | ((unsigned)hi << 16);
}
__device__ __forceinline__ bf16x8 ones_frag() {
    union { bf16x8 v; unsigned short s[8]; } u;
    #pragma unroll
    for (int i = 0; i < 8; ++i) u.s[i] = 0x3F80;   // bf16 1.0
    return u.v;
}

// ------- Kernel 1: partial KV, direct gather, deep load clauses -------
// grid (NSPL, 2, BN), 512 threads. wave w: head = 4*hg + (w>>1), dhalf = w&1.
template<int NSPL>
__global__ void __launch_bounds__(512, 2)
la_kv_direct2(const float* __restrict__ Kg, const float* __restrict__ Vg,
              const float* __restrict__ Mg, float* __restrict__ ws)
{
    constexpr int SR = Sc / NSPL;      // 128 s-rows per block
    constexpr int NT = SR / 32;        // 4 tiles of 32

    const int t     = threadIdx.x;
    const int lane  = t & 63;
    const int w     = t >> 6;          // 0..7
    const int frow  = lane & 15;
    const int kg    = lane >> 4;       // k-group 0..3 -> s-offsets 8kg..8kg+7
    const int sp    = blockIdx.x;
    const int hg    = blockIdx.y;      // head-quad 0..1
    const int bn    = blockIdx.z;
    const int b     = bn >> 3;
    const int h     = 4 * hg + (w >> 1);
    const int dhalf = w & 1;

    const size_t base  = (size_t)bn * Sc * HD + (size_t)h * Dc;
    const size_t mbase = (size_t)b * Sc;
    const int    sbase = sp * SR;

    f32x4 acc[2][4];                   // [d-chunk within half][m-chunk]
    f32x4 aks[2];
    #pragma unroll
    for (int c = 0; c < 2; ++c) {
        aks[c] = (f32x4){0.f, 0.f, 0.f, 0.f};
        #pragma unroll
        for (int ms = 0; ms < 4; ++ms) acc[c][ms] = (f32x4){0.f, 0.f, 0.f, 0.f};
    }
    const bf16x8 ones = ones_frag();
    union uf { bf16x8 v; unsigned short s[8]; };

    #pragma unroll 1
    for (int it = 0; it < NT; ++it) {
        const int sb = sbase + it * 32 + 8 * kg;          // this lane's s-base
        const float* kp = Kg + base + (size_t)sb * HD + 32 * dhalf + frow;
        const float* vp = Vg + base + (size_t)sb * HD + frow;
        const float* mp = Mg + mbase + sb;

        // ---- hoist ALL loads of this tile (deep clause, ~56 outstanding) ----
        float ml[8];
        #pragma unroll
        for (int j = 0; j < 8; ++j) ml[j] = mp[j];
        float ka[2][8];
        #pragma unroll
        for (int c = 0; c < 2; ++c)
            #pragma unroll
            for (int j = 0; j < 8; ++j) ka[c][j] = kp[(size_t)j * HD + 16 * c];
        float vb[4][8];
        #pragma unroll
        for (int ms = 0; ms < 4; ++ms)
            #pragma unroll
            for (int j = 0; j < 8; ++j) vb[ms][j] = vp[(size_t)j * HD + 16 * ms];

        // ---- convert K, ksum MFMA ----
        uf kh[2], kl[2];
        #pragma unroll
        for (int c = 0; c < 2; ++c) {
            #pragma unroll
            for (int j = 0; j < 8; ++j)
                splitbf(elup1(ka[c][j]) * ml[j], kh[c].s[j], kl[c].s[j]);
            aks[c] = __builtin_amdgcn_mfma_f32_16x16x32_bf16(kh[c].v, ones, aks[c], 0, 0, 0);
            aks[c] = __builtin_amdgcn_mfma_f32_16x16x32_bf16(kl[c].v, ones, aks[c], 0, 0, 0);
        }
        // ---- convert V, accumulate ----
        #pragma unroll
        for (int ms = 0; ms < 4; ++ms) {
            uf vh, vl;
            #pragma unroll
            for (int j = 0; j < 8; ++j) splitbf(vb[ms][j], vh.s[j], vl.s[j]);
            #pragma unroll
            for (int c = 0; c < 2; ++c) {
                acc[c][ms] = __builtin_amdgcn_mfma_f32_16x16x32_bf16(kh[c].v, vh.v, acc[c][ms], 0, 0, 0);
                acc[c][ms] = __builtin_amdgcn_mfma_f32_16x16x32_bf16(kh[c].v, vl.v, acc[c][ms], 0, 0, 0);
                acc[c][ms] = __builtin_amdgcn_mfma_f32_16x16x32_bf16(kl[c].v, vh.v, acc[c][ms], 0, 0, 0);
            }
        }
    }

    // write this wave's (head h, d-half) partial slice
    float* outp = ws + (size_t)((bn * 8 + h) * NSPL + sp) * PARTIAL;
    #pragma unroll
    for (int c = 0; c < 2; ++c)
        #pragma unroll
        for (int ms = 0; ms < 4; ++ms)
            #pragma unroll
            for (int r = 0; r < 4; ++r)
                outp[(32 * dhalf + 16 * c + 4 * kg + r) * Mc + 16 * ms + frow] = acc[c][ms][r];

    if (frow == 0) {
        #pragma unroll
        for (int c = 0; c < 2; ++c)
            #pragma unroll
            for (int r = 0; r < 4; ++r)
                outp[Dc * Mc + 32 * dhalf + 16 * c + 4 * kg + r] = aks[c][r];
    }
}

// ------- Kernel 1R: reduce NSPL partials in place into partial slot 0 -------
template<int NSPL>
__global__ void __launch_bounds__(256, 8)
la_reduce(float* __restrict__ ws)
{
    constexpr int NF4 = PARTIAL / 4;     // 1040 float4s
    constexpr int QW  = NF4 / 4;         // 260 per quarter-block
    const int g = blockIdx.y;            // group 0..255
    const int q = blockIdx.x;            // quarter 0..3
    const int t = threadIdx.x;

    float4* base = reinterpret_cast<float4*>(ws + (size_t)g * NSPL * PARTIAL);
    for (int i = q * QW + t; i < (q + 1) * QW; i += 256) {
        float4 s = base[i];
        #pragma unroll
        for (int sp = 1; sp < NSPL; ++sp) {
            const float4 p = base[sp * NF4 + i];
            s.x += p.x; s.y += p.y; s.z += p.z; s.w += p.w;
        }
        base[i] = s;                     // in-place: slot 0 now holds the sum
    }
}

// ---------------- Kernel 2: output via split-bf16 MFMA (verified) ----------
template<int NSUM>
__global__ void __launch_bounds__(256, 4)
la_out_mfma(const float* __restrict__ Qg, const float* __restrict__ ws,
            float* __restrict__ Og, int pstride)
{
    __shared__ unsigned short kvh[Mc][PADD];  // KV hi [m][d]
    __shared__ unsigned short kvl[Mc][PADD];  // KV lo
    __shared__ unsigned short ksh[64];        // ksum hi
    __shared__ unsigned short ksl[64];        // ksum lo
    __shared__ unsigned short qhh[64][PADD];  // phiQ hi [l][d]
    __shared__ unsigned short qll[64][PADD];  // phiQ lo

    const int t    = threadIdx.x;
    const int tx   = t & 15;
    const int tyq  = t >> 4;
    const int lane = t & 63;
    const int w    = t >> 6;
    const int g    = blockIdx.y;
    const int ls   = blockIdx.x;
    const int h    = g & 7;
    const int bn   = g >> 3;

    const size_t rowbase = (size_t)bn * Lc * HD + (size_t)h * Dc;
    const float* pw = ws + (size_t)g * pstride * PARTIAL;
    const int lbase = ls * LROWS;

    float4 qr[4];
    auto loadB = [&](int it) {
        const int l0 = lbase + it * 64 + 4 * tyq;
        #pragma unroll
        for (int j = 0; j < 4; ++j)
            qr[j] = *reinterpret_cast<const float4*>(Qg + rowbase + (size_t)(l0 + j) * HD + 4 * tx);
    };
    auto storeB = [&]() {
        #pragma unroll
        for (int j = 0; j < 4; ++j) {
            const int r = 4 * tyq + j;
            const float q[4] = {qr[j].x, qr[j].y, qr[j].z, qr[j].w};
            unsigned short h0, l0, h1, l1, h2, l2, h3, l3;
            splitbf(elup1(q[0]), h0, l0);
            splitbf(elup1(q[1]), h1, l1);
            splitbf(elup1(q[2]), h2, l2);
            splitbf(elup1(q[3]), h3, l3);
            uint2 ph, pl;
            ph.x = pack2(h0, h1); ph.y = pack2(h2, h3);
            pl.x = pack2(l0, l1); pl.y = pack2(l2, l3);
            *reinterpret_cast<uint2*>(&qhh[r][4 * tx]) = ph;
            *reinterpret_cast<uint2*>(&qll[r][4 * tx]) = pl;
        }
    };

    loadB(0);
    #pragma unroll
    for (int e = 0; e < 16; ++e) {
        const int idx = t + 256 * e;
        float s = 0.f;
        #pragma unroll
        for (int sp = 0; sp < NSUM; ++sp) s += pw[sp * PARTIAL + idx];
        unsigned short hh, ll;
        splitbf(s, hh, ll);
        kvh[idx & 63][idx >> 6] = hh;
        kvl[idx & 63][idx >> 6] = ll;
    }
    if (t < 64) {
        float s = 0.f;
        #pragma unroll
        for (int sp = 0; sp < NSUM; ++sp) s += pw[sp * PARTIAL + Dc * Mc + t];
        unsigned short hh, ll;
        splitbf(s, hh, ll);
        ksh[t] = hh;
        ksl[t] = ll;
    }
    storeB();
    __syncthreads();

    const int fcol = 8 * (lane >> 4);
    const int frow = lane & 15;
    const size_t obase = (size_t)bn * Lc * HD + (size_t)h * Mc;

    for (int it = 0; it < NTL; ++it) {
        if (it + 1 < NTL) loadB(it + 1);
        union { bf16x8 v; uint2 u[2]; } fah0, fal0, fah1, fal1;
        {
            const uint2* p;
            p = reinterpret_cast<const uint2*>(&qhh[16 * w + frow][fcol]);      fah0.u[0] = p[0]; fah0.u[1] = p[1];
            p = reinterpret_cast<const uint2*>(&qll[16 * w + frow][fcol]);      fal0.u[0] = p[0]; fal0.u[1] = p[1];
            p = reinterpret_cast<const uint2*>(&qhh[16 * w + frow][32 + fcol]); fah1.u[0] = p[0]; fah1.u[1] = p[1];
            p = reinterpret_cast<const uint2*>(&qll[16 * w + frow][32 + fcol]); fal1.u[0] = p[0]; fal1.u[1] = p[1];
        }
        f32x4 acc[4], accz;
        #pragma unroll
        for (int ms = 0; ms < 4; ++ms) acc[ms] = (f32x4){0.f, 0.f, 0.f, 0.f};
        accz = (f32x4){0.f, 0.f, 0.f, 0.f};

        #pragma unroll
        for (int ks = 0; ks < 2; ++ks) {
            const bf16x8 fh = ks ? fah1.v : fah0.v;
            const bf16x8 fl = ks ? fal1.v : fal0.v;
            #pragma unroll
            for (int ms = 0; ms < 4; ++ms) {
                union { bf16x8 v; uint2 u[2]; } fbh, fbl;
                const uint2* ph = reinterpret_cast<const uint2*>(&kvh[16 * ms + frow][32 * ks + fcol]);
                fbh.u[0] = ph[0]; fbh.u[1] = ph[1];
                const uint2* pl = reinterpret_cast<const uint2*>(&kvl[16 * ms + frow][32 * ks + fcol]);
                fbl.u[0] = pl[0]; fbl.u[1] = pl[1];
                acc[ms] = __builtin_amdgcn_mfma_f32_16x16x32_bf16(fh, fbh.v, acc[ms], 0, 0, 0);
                acc[ms] = __builtin_amdgcn_mfma_f32_16x16x32_bf16(fh, fbl.v, acc[ms], 0, 0, 0);
                acc[ms] = __builtin_amdgcn_mfma_f32_16x16x32_bf16(fl, fbh.v, acc[ms], 0, 0, 0);
            }
            union { bf16x8 v; uint2 u[2]; } fzh, fzl;
            const uint2* ph = reinterpret_cast<const uint2*>(&ksh[32 * ks + fcol]);
            fzh.u[0] = ph[0]; fzh.u[1] = ph[1];
            const uint2* pl = reinterpret_cast<const uint2*>(&ksl[32 * ks + fcol]);
            fzl.u[0] = pl[0]; fzl.u[1] = pl[1];
            accz = __builtin_amdgcn_mfma_f32_16x16x32_bf16(fh, fzh.v, accz, 0, 0, 0);
            accz = __builtin_amdgcn_mfma_f32_16x16x32_bf16(fh, fzl.v, accz, 0, 0, 0);
            accz = __builtin_amdgcn_mfma_f32_16x16x32_bf16(fl, fzh.v, accz, 0, 0, 0);
        }

        const int lt = lbase + it * 64 + 16 * w + 4 * (lane >> 4);
        #pragma unroll
        for (int r = 0; r < 4; ++r) {
            const float z = 1.0f / (accz[r] + EPSF);
            const size_t ro = obase + (size_t)(lt + r) * HD + frow;
            #pragma unroll
            for (int ms = 0; ms < 4; ++ms)
                Og[ro + 16 * ms] = acc[ms][r] * z;
        }
        __syncthreads();
        if (it + 1 < NTL) storeB();
        __syncthreads();
    }
}

// ---------------- Fallback: fp32 fused kernel (verified R1) ----------------
__global__ void __launch_bounds__(256, 1)
la_fused_kernel(const float* __restrict__ Qg, const float* __restrict__ Kg,
                const float* __restrict__ Vg, const float* __restrict__ Mg,
                float* __restrict__ Og)
{
    __shared__ float lk[32][Dc];
    __shared__ float lv[32][Mc];
    __shared__ float kvt[Dc][Mc];
    __shared__ float ksm[Dc];
    __shared__ float qt[Dc][64];

    const int t  = threadIdx.x;
    const int tx = t & 15;
    const int ty = t >> 4;
    const int g  = blockIdx.x;
    const int h  = g & 7;
    const int bn = g >> 3;
    const int b  = g >> 6;

    const size_t rowbase = (size_t)bn * Sc * HD + (size_t)h * Dc;
    const size_t mbase   = (size_t)b * Sc;

    const int d0 = tx * 4, m0 = ty * 4, c4 = tx * 4, r0 = ty;

    float acc[4][4] = {{0.f,0.f,0.f,0.f},{0.f,0.f,0.f,0.f},{0.f,0.f,0.f,0.f},{0.f,0.f,0.f,0.f}};
    float ks[4] = {0.f, 0.f, 0.f, 0.f};
    float4 kr[2], vr[2];
    float  mr[2];

    auto loadA = [&](int it) {
        const int s0 = it * 32;
        #pragma unroll
        for (int k = 0; k < 2; ++k) {
            const int r = r0 + 16 * k;
            const size_t off = rowbase + (size_t)(s0 + r) * HD + c4;
            kr[k] = *reinterpret_cast<const float4*>(Kg + off);
            vr[k] = *reinterpret_cast<const float4*>(Vg + off);
            mr[k] = Mg[mbase + s0 + r];
        }
    };
    auto storeA = [&]() {
        #pragma unroll
        for (int k = 0; k < 2; ++k) {
            const int r = r0 + 16 * k;
            float4 kk;
            kk.x = elup1(kr[k].x) * mr[k];
            kk.y = elup1(kr[k].y) * mr[k];
            kk.z = elup1(kr[k].z) * mr[k];
            kk.w = elup1(kr[k].w) * mr[k];
            *reinterpret_cast<float4*>(&lk[r][c4]) = kk;
            *reinterpret_cast<float4*>(&lv[r][c4]) = vr[k];
        }
    };

    loadA(0);
    storeA();
    __syncthreads();
    for (int it = 0; it < Sc / 32; ++it) {
        if (it + 1 < Sc / 32) loadA(it + 1);
        #pragma unroll 8
        for (int r = 0; r < 32; ++r) {
            const float4 k4 = *reinterpret_cast<const float4*>(&lk[r][d0]);
            const float4 v4 = *reinterpret_cast<const float4*>(&lv[r][m0]);
            const float kk[4] = {k4.x, k4.y, k4.z, k4.w};
            const float vv[4] = {v4.x, v4.y, v4.z, v4.w};
            ks[0] += kk[0]; ks[1] += kk[1]; ks[2] += kk[2]; ks[3] += kk[3];
            #pragma unroll
            for (int i = 0; i < 4; ++i)
                #pragma unroll
                for (int j = 0; j < 4; ++j)
                    acc[i][j] += kk[i] * vv[j];
        }
        __syncthreads();
        if (it + 1 < Sc / 32) storeA();
        __syncthreads();
    }

    #pragma unroll
    for (int i = 0; i < 4; ++i) {
        float4 w;
        w.x = acc[i][0]; w.y = acc[i][1]; w.z = acc[i][2]; w.w = acc[i][3];
        *reinterpret_cast<float4*>(&kvt[d0 + i][m0]) = w;
    }
    if (ty == 0) {
        #pragma unroll
        for (int i = 0; i < 4; ++i) ksm[d0 + i] = ks[i];
    }
    __syncthreads();

    float4 qr[4];
    auto loadB = [&](int it) {
        const int l0 = it * 64;
        #pragma unroll
        for (int k = 0; k < 4; ++k) {
            const int r = r0 + 16 * k;
            const size_t off = rowbase + (size_t)(l0 + r) * HD + c4;
            qr[k] = *reinterpret_cast<const float4*>(Qg + off);
        }
    };
    const int swzw = (tx & 7) << 2;
    auto storeB = [&]() {
        #pragma unroll
        for (int k = 0; k < 4; ++k) {
            const int r = r0 + 16 * k;
            const int lidx = r ^ swzw;
            qt[c4 + 0][lidx] = elup1(qr[k].x);
            qt[c4 + 1][lidx] = elup1(qr[k].y);
            qt[c4 + 2][lidx] = elup1(qr[k].z);
            qt[c4 + 3][lidx] = elup1(qr[k].w);
        }
    };

    loadB(0);
    storeB();
    __syncthreads();
    for (int it = 0; it < Lc / 64; ++it) {
        if (it + 1 < Lc / 64) loadB(it + 1);
        float accB[4][4] = {{0.f,0.f,0.f,0.f},{0.f,0.f,0.f,0.f},{0.f,0.f,0.f,0.f},{0.f,0.f,0.f,0.f}};
        float za[4] = {0.f, 0.f, 0.f, 0.f};
        #pragma unroll 8
        for (int d = 0; d < Dc; ++d) {
            const int swz = ((d >> 2) & 7) << 2;
            const float4 q4  = *reinterpret_cast<const float4*>(&qt[d][(4 * ty) ^ swz]);
            const float4 kv4 = *reinterpret_cast<const float4*>(&kvt[d][4 * tx]);
            const float kd = ksm[d];
            const float qq[4] = {q4.x, q4.y, q4.z, q4.w};
            const float kv[4] = {kv4.x, kv4.y, kv4.z, kv4.w};
            #pragma unroll
            for (int i = 0; i < 4; ++i) {
                za[i] += qq[i] * kd;
                #pragma unroll
                for (int j = 0; j < 4; ++j)
                    accB[i][j] += qq[i] * kv[j];
            }
        }
        const int l0 = it * 64;
        const size_t obase = (size_t)bn * Lc * HD + (size_t)h * Mc;
        #pragma unroll
        for (int i = 0; i < 4; ++i) {
            const int l = l0 + 4 * ty + i;
            const float z = 1.0f / (za[i] + EPSF);
            float4 o;
            o.x = accB[i][0] * z; o.y = accB[i][1] * z;
            o.z = accB[i][2] * z; o.w = accB[i][3] * z;
            *reinterpret_cast<float4*>(Og + obase + (size_t)l * HD + 4 * tx) = o;
        }
        __syncthreads();
        if (it + 1 < Lc / 64) storeB();
        __syncthreads();
    }
}

extern "C" void kernel_launch(void* const* d_in, const int* in_sizes, int n_in,
                              void* d_out, int out_size, void* d_ws, size_t ws_size,
                              hipStream_t stream) {
    const float* Qg = (const float*)d_in[0];
    const float* Kg = (const float*)d_in[1];
    const float* Vg = (const float*)d_in[2];
    const float* Mg = (const float*)d_in[3];
    float* Og = (float*)d_out;

    const size_t need8 = (size_t)GROUPS * 8 * PARTIAL * sizeof(float);
    if (ws_size >= need8) {
        float* ws = (float*)d_ws;
        hipLaunchKernelGGL((la_kv_direct2<8>), dim3(8, 2, BN), dim3(512), 0, stream,
                           Kg, Vg, Mg, ws);
        hipLaunchKernelGGL((la_reduce<8>), dim3(4, GROUPS), dim3(256), 0, stream,
                           ws);
        hipLaunchKernelGGL((la_out_mfma<1>), dim3(LSPLITS, GROUPS), dim3(256), 0, stream,
                           Qg, ws, Og, 8);
    } else {
        hipLaunchKernelGGL(la_fused_kernel, dim3(GROUPS), dim3(256), 0, stream,
                           Qg, Kg, Vg, Mg, Og);
    }
}